// Round 10
// baseline (1059.376 us; speedup 1.0000x reference)
//
#include <hip/hip_runtime.h>

#define NBATCH 64
#define NCH    128
#define NTYPE  6
#define NK     127
#define N1     25
#define N2     50
#define N3     100
#define NAXIS  4
#define OUTPER 400  // N3*NAXIS

// ---------- repetition macros: straight-line code, literal indices ONLY ----------
#define R5(M)  M(0) M(1) M(2) M(3) M(4)
#define R5A(M,a) M(a,0) M(a,1) M(a,2) M(a,3) M(a,4)
#define R7(M)  M(0) M(1) M(2) M(3) M(4) M(5) M(6)
#define R12(M) M(0) M(1) M(2) M(3) M(4) M(5) M(6) M(7) M(8) M(9) M(10) M(11)
#define R25(M) M(0) M(1) M(2) M(3) M(4) M(5) M(6) M(7) M(8) M(9) M(10) M(11) M(12) \
               M(13) M(14) M(15) M(16) M(17) M(18) M(19) M(20) M(21) M(22) M(23) M(24)
#define R25A(M,a) M(a,0) M(a,1) M(a,2) M(a,3) M(a,4) M(a,5) M(a,6) M(a,7) M(a,8) M(a,9) \
               M(a,10) M(a,11) M(a,12) M(a,13) M(a,14) M(a,15) M(a,16) M(a,17) M(a,18) \
               M(a,19) M(a,20) M(a,21) M(a,22) M(a,23) M(a,24)
#define R50(M) R25(M) M(25) M(26) M(27) M(28) M(29) M(30) M(31) M(32) M(33) M(34) \
               M(35) M(36) M(37) M(38) M(39) M(40) M(41) M(42) M(43) M(44) M(45) \
               M(46) M(47) M(48) M(49)

__device__ __forceinline__ float tanh_fast(float x) {
    float e = __expf(2.0f * x);                       // e^{2x}; inf/0 saturate correctly
    return 1.0f - 2.0f * __builtin_amdgcn_rcpf(e + 1.0f);
}

// coords (NB,NC,3) -> ct[(j*3+d)*NB + b]  (lane=b contiguous)
__global__ void k_transpose(const float* __restrict__ coords, float* __restrict__ ct) {
    int t = blockIdx.x * blockDim.x + threadIdx.x;
    if (t >= NBATCH * NCH * 3) return;
    int b  = t & (NBATCH - 1);
    int jd = t >> 6;
    int d  = jd % 3;
    int j  = jd / 3;
    ct[t] = coords[(b * NCH + j) * 3 + d];
}

// single-thread counting sort of k=0..126 keyed by types[j(k)], via LDS-staged types.
// Sorted order groups k's by channel -> W2/W3 scalar loads K$-hot
// (proven round 9: FETCH 360 MB -> 14 MB).
__device__ __forceinline__ void sort_k_by_type(
    const int* __restrict__ types, int n, int* tysh, int* ks, int* bins, int tid, int nthr)
{
    for (int t = tid; t < NCH; t += nthr) tysh[t] = types[t];
    __syncthreads();
    if (tid == 0) {
        for (int t = 0; t < NTYPE; ++t) bins[t] = 0;
        for (int k = 0; k < NK; ++k) { int j = (k < n) ? k : k + 1; bins[tysh[j]]++; }
        int off = 0;
        for (int t = 0; t < NTYPE; ++t) { int c = bins[t]; bins[t] = off; off += c; }
        for (int k = 0; k < NK; ++k) { int j = (k < n) ? k : k + 1; ks[bins[tysh[j]]++] = k; }
    }
    __syncthreads();
}

// Kernel A: t1[n, a*4+f, b] = sum_k env_a * out4_f.  wave=(n, 8-k slice), lane=b.
__global__ __launch_bounds__(256, 4) void k_mlp(
    const float* __restrict__ ct, const int* __restrict__ types,
    const float* __restrict__ W1, const float* __restrict__ B1,
    const float* __restrict__ W2, const float* __restrict__ B2,
    const float* __restrict__ W3, const float* __restrict__ B3,
    float* __restrict__ t1buf)
{
    __shared__ int ks[NK];
    __shared__ int tysh[NCH];
    __shared__ int bins[NTYPE];

    const int n  = blockIdx.x >> 2;
    const int qc = blockIdx.x & 3;
    const int w  = threadIdx.x >> 6;
    const int b  = threadIdx.x & 63;
    const int k0 = qc * 32 + w * 8;

    sort_k_by_type(types, n, tysh, ks, bins, threadIdx.x, 256);

    const float cx = ct[(n*3+0)*NBATCH + b];
    const float cy = ct[(n*3+1)*NBATCH + b];
    const float cz = ct[(n*3+2)*NBATCH + b];
    const int tn = __builtin_amdgcn_readfirstlane(tysh[n]);

    float t1a[12];
#define TIN(i) t1a[i] = 0.0f;
    R12(TIN)
#undef TIN

    for (int kk = 0; kk < 8; ++kk) {
        const int kidx = k0 + kk;
        if (kidx >= NK) break;
        const int sk = __builtin_amdgcn_readfirstlane(ks[kidx]);
        const int j  = (sk < n) ? sk : sk + 1;
        const int ch = __builtin_amdgcn_readfirstlane(tn * NTYPE + tysh[j]);

        const float dx = cx - ct[(j*3+0)*NBATCH + b];
        const float dy = cy - ct[(j*3+1)*NBATCH + b];
        const float dz = cz - ct[(j*3+2)*NBATCH + b];
        const float d2 = dx*dx + dy*dy + dz*dz;
        const float dd = sqrtf(d2);
        const float dinv = __builtin_amdgcn_rcpf(fmaxf(dd, 1e-12f));
        const float di2 = dinv * dinv;
        const float ax = dx * di2, ay = dy * di2, az = dz * di2;

        const float* w1r = W1 + ch * N1;
        const float* b1r = B1 + ch * N1;
        float y1[N1];
#define L1S(o) y1[o] = tanh_fast(fmaf(dinv, w1r[o], b1r[o]));
        R25(L1S)
#undef L1S

        const float* w2r = W2 + ch * (N2 * N1);
        const float* b2r = B2 + ch * N2;
        const float* w3r = W3 + ch * (N3 * N2);
        float zf[4];
        zf[0] = B3[ch*N3+0]; zf[1] = B3[ch*N3+1];
        zf[2] = B3[ch*N3+2]; zf[3] = B3[ch*N3+3];
        float r[4];
#define MLP2I(o,i) z = fmaf(w2r[(o)*N1+(i)], y1[i], z);
#define MLP2(o) { float z = b2r[o]; R25A(MLP2I,o) \
        float y2o = tanh_fast(z) + y1[(o)%N1]; \
        if ((o) < 4) r[(o)&3] = y2o; \
        zf[0] = fmaf(w3r[0*N2+(o)], y2o, zf[0]); \
        zf[1] = fmaf(w3r[1*N2+(o)], y2o, zf[1]); \
        zf[2] = fmaf(w3r[2*N2+(o)], y2o, zf[2]); \
        zf[3] = fmaf(w3r[3*N2+(o)], y2o, zf[3]); }
        R50(MLP2)
#undef MLP2
#undef MLP2I

#define O4F(f) { float o4 = tanh_fast(zf[f]) + r[f]; \
        t1a[0+(f)] = fmaf(ax, o4, t1a[0+(f)]); \
        t1a[4+(f)] = fmaf(ay, o4, t1a[4+(f)]); \
        t1a[8+(f)] = fmaf(az, o4, t1a[8+(f)]); }
        O4F(0) O4F(1) O4F(2) O4F(3)
#undef O4F
    }

    float* dst = t1buf + (n * 12) * NBATCH + b;   // [n][i][b] lane-coalesced
#define TAT(i) atomicAdd(dst + (i) * NBATCH, t1a[i]);
    R12(TAT)
#undef TAT
}

// Kernel B: block = (n, gh, kh) -> 512 blocks = 2 co-resident/CU (round 9 had
// 1/CU, 2 waves/SIMD -> VALUBusy 28%). Each block: 64 sorted k's.
// y2t transposed to [kk][i][b]: P1 writes and P2 reads both lane-contiguous,
// conflict-free, no pad, 51.2 KB. y2v in 5-wide chunks + per-chunk coord
// reload keep P1 live ~58 / P2 live ~50 < the 64-VGPR cap (the round-9 spill
// source: WRITE 311 MB). Two kh blocks combine via 2-way atomicAdd into
// zeroed out.
__global__ __launch_bounds__(512, 4) void k_res2(
    const float* __restrict__ ct, const int* __restrict__ types,
    const float* __restrict__ W1, const float* __restrict__ B1,
    const float* __restrict__ W2, const float* __restrict__ B2,
    const float* __restrict__ W3, const float* __restrict__ B3,
    const float* __restrict__ t1buf, float* __restrict__ out)
{
    __shared__ float y2t[4 * N2 * NBATCH];         // [kk][i][b] 51200 B
    __shared__ float t2s[4 * NBATCH * NAXIS];      //  4096 B
    __shared__ float t1s[12 * NBATCH];             //  3072 B
    __shared__ int   ks[NK];
    __shared__ int   tysh[NCH];
    __shared__ int   bins[NTYPE];

    const int n    = blockIdx.x >> 2;
    const int gh   = (blockIdx.x >> 1) & 1;
    const int kh   = blockIdx.x & 1;
    const int w    = threadIdx.x >> 6;
    const int lane = threadIdx.x & 63;            // = b in both phases
    const int kk2  = w >> 1;                      // phase-1 k of chunk
    const int h    = w & 1;                       // phase-1 y2 half
    const int k_end = kh ? NK : 64;

    // stage t1 into LDS (768 floats); sort's barrier covers the hazard
    t1s[threadIdx.x] = t1buf[n*768 + threadIdx.x];
    if (threadIdx.x < 256) t1s[512 + threadIdx.x] = t1buf[n*768 + 512 + threadIdx.x];
    sort_k_by_type(types, n, tysh, ks, bins, threadIdx.x, 512);

    const int tn = __builtin_amdgcn_readfirstlane(tysh[n]);

    const int g0 = __builtin_amdgcn_readfirstlane(w * 7);   // wave-uniform
    int gg[7];
#define GGI(gi) gg[gi] = ((g0 + (gi)) < N2) ? (g0 + (gi)) : (N2 - 1);
    R7(GGI)
#undef GGI

    float racc[7][4];
#define RIN(gi) racc[gi][0]=0.f; racc[gi][1]=0.f; racc[gi][2]=0.f; racc[gi][3]=0.f;
    R7(RIN)
#undef RIN

    for (int kc = 0; kc < 16; ++kc) {
        const int kb = kh * 64 + kc * 4;
        // ================= phase 1: stage y2 (+t2) for 4 sorted k's =================
        {
            const int kidx = kb + kk2;
            if (kidx < k_end) {
                const int sk = __builtin_amdgcn_readfirstlane(ks[kidx]);
                const int j  = (sk < n) ? sk : sk + 1;
                const int ch = __builtin_amdgcn_readfirstlane(tn * NTYPE + tysh[j]);
                // coords reloaded per chunk (L1-hot) instead of held live
                const float dx = ct[(n*3+0)*NBATCH + lane] - ct[(j*3+0)*NBATCH + lane];
                const float dy = ct[(n*3+1)*NBATCH + lane] - ct[(j*3+1)*NBATCH + lane];
                const float dz = ct[(n*3+2)*NBATCH + lane] - ct[(j*3+2)*NBATCH + lane];
                const float d2 = dx*dx + dy*dy + dz*dz;
                const float dd = sqrtf(d2);
                const float dinv = __builtin_amdgcn_rcpf(fmaxf(dd, 1e-12f));

                if (h == 0) {
                    const float di2 = dinv * dinv;
                    const float ax = dx * di2, ay = dy * di2, az = dz * di2;
#define T2W(f) t2s[(kk2*NBATCH + lane)*NAXIS + (f)] = \
                    ax*t1s[(0+(f))*NBATCH+lane] + ay*t1s[(4+(f))*NBATCH+lane] \
                  + az*t1s[(8+(f))*NBATCH+lane];
                    T2W(0) T2W(1) T2W(2) T2W(3)
#undef T2W
                }

                const float* w1r = W1 + ch * N1;
                const float* b1r = B1 + ch * N1;
                float y1[N1];
#define L1S(o) y1[o] = tanh_fast(fmaf(dinv, w1r[o], b1r[o]));
                R25(L1S)
#undef L1S
                const int ob = h * N1;            // 0 or 25
                const float* w2h = W2 + ch * (N2*N1) + ob * N1;
                const float* b2h = B2 + ch * N2 + ob;
                float* y2w = &y2t[(kk2*N2 + ob)*NBATCH + lane];
#define P1I(oi,i) z = fmaf(w2h[(oi)*N1+(i)], y1[i], z);
#define P1S(oi) { float z = b2h[oi]; R25A(P1I,oi) \
                  y2w[(oi)*NBATCH] = tanh_fast(z) + y1[oi]; }
                R25(P1S)
#undef P1S
#undef P1I
            }
        }
        __syncthreads();
        // ================= phase 2: layer 3 + contractions =================
        for (int kk = 0; kk < 4; ++kk) {
            const int kidx = kb + kk;
            if (kidx >= k_end) break;
            const int sk = __builtin_amdgcn_readfirstlane(ks[kidx]);
            const int j  = (sk < n) ? sk : sk + 1;
            const int ch = __builtin_amdgcn_readfirstlane(tn * NTYPE + tysh[j]);

            const float* w3b = W3 + ch * (N3*N2) + (gh*N2) * N2;
            const float* b3b = B3 + ch * N3 + gh * N2;
            const float* y2r = &y2t[(kk*N2)*NBATCH + lane];

            float z[7];
#define ZIN(gi) z[gi] = b3b[gg[gi]];
            R7(ZIN)
#undef ZIN
            for (int ic = 0; ic < 10; ++ic) {      // 10 chunks of 5: live set small
                const int io = ic * 5;
                float y2v[5];
#define LDY(i) y2v[i] = y2r[(io + (i))*NBATCH];
                R5(LDY)
#undef LDY
#define FMA1(gi,i) z[gi] = fmaf(w3b[gg[gi]*N2 + io + (i)], y2v[i], z[gi]);
#define FMAG(gi) R5A(FMA1,gi)
                R7(FMAG)
#undef FMAG
#undef FMA1
            }
            const float4 t2v = *(const float4*)&t2s[(kk*NBATCH + lane)*NAXIS];
#define PFIN(gi) { float rv = y2r[gg[gi]*NBATCH]; \
                   float o3 = tanh_fast(z[gi]) + rv; \
                   racc[gi][0] = fmaf(o3, t2v.x, racc[gi][0]); \
                   racc[gi][1] = fmaf(o3, t2v.y, racc[gi][1]); \
                   racc[gi][2] = fmaf(o3, t2v.z, racc[gi][2]); \
                   racc[gi][3] = fmaf(o3, t2v.w, racc[gi][3]); }
            R7(PFIN)
#undef PFIN
        }
        __syncthreads();
    }

#define PST(gi) if (g0 + (gi) < N2) { \
        float* dp = &out[(lane*NCH + n)*OUTPER + (gh*N2 + g0 + (gi))*NAXIS]; \
        atomicAdd(dp + 0, racc[gi][0]); \
        atomicAdd(dp + 1, racc[gi][1]); \
        atomicAdd(dp + 2, racc[gi][2]); \
        atomicAdd(dp + 3, racc[gi][3]); }
    R7(PST)
#undef PST
}

extern "C" void kernel_launch(void* const* d_in, const int* in_sizes, int n_in,
                              void* d_out, int out_size, void* d_ws, size_t ws_size,
                              hipStream_t stream) {
    const float* coords = (const float*)d_in[0];
    const int*   types  = (const int*)d_in[1];
    const float* W1 = (const float*)d_in[2];
    const float* B1 = (const float*)d_in[3];
    const float* W2 = (const float*)d_in[4];
    const float* B2 = (const float*)d_in[5];
    const float* W3 = (const float*)d_in[6];
    const float* B3 = (const float*)d_in[7];
    float* out = (float*)d_out;

    float* t1buf = (float*)d_ws;                          // 128*12*64 floats
    float* ct    = t1buf + NCH * 12 * NBATCH;             // 64*128*3 floats

    hipMemsetAsync(t1buf, 0, (size_t)NCH * 12 * NBATCH * sizeof(float), stream);
    hipMemsetAsync(out, 0, (size_t)out_size * sizeof(float), stream);

    k_transpose<<<(NBATCH*NCH*3 + 255)/256, 256, 0, stream>>>(coords, ct);
    k_mlp <<<NCH*4, 256, 0, stream>>>(ct, types, W1,B1,W2,B2,W3,B3, t1buf);
    k_res2<<<NCH*4, 512, 0, stream>>>(ct, types, W1,B1,W2,B2,W3,B3, t1buf, out);
}

// Round 11
// 830.737 us; speedup vs baseline: 1.2752x; 1.2752x over previous
//
#include <hip/hip_runtime.h>

#define NBATCH 64
#define NCH    128
#define NTYPE  6
#define NK     127
#define N1     25
#define N2     50
#define N3     100
#define NAXIS  4
#define OUTPER 400  // N3*NAXIS
#define W2P    28   // W2 row padded to 28 floats -> every row 16B-aligned (float4 reads)
#define MAXKP  152  // padded sorted-k capacity (127 + 6*3 = 145)
#define MAXC4  38   // max 4-k chunks

// ---------- repetition macros: straight-line code, literal indices ONLY ----------
#define R5(M)  M(0) M(1) M(2) M(3) M(4)
#define R7(M)  M(0) M(1) M(2) M(3) M(4) M(5) M(6)
#define R12(M) M(0) M(1) M(2) M(3) M(4) M(5) M(6) M(7) M(8) M(9) M(10) M(11)
#define R25(M) M(0) M(1) M(2) M(3) M(4) M(5) M(6) M(7) M(8) M(9) M(10) M(11) M(12) \
               M(13) M(14) M(15) M(16) M(17) M(18) M(19) M(20) M(21) M(22) M(23) M(24)
#define R25A(M,a) M(a,0) M(a,1) M(a,2) M(a,3) M(a,4) M(a,5) M(a,6) M(a,7) M(a,8) M(a,9) \
               M(a,10) M(a,11) M(a,12) M(a,13) M(a,14) M(a,15) M(a,16) M(a,17) M(a,18) \
               M(a,19) M(a,20) M(a,21) M(a,22) M(a,23) M(a,24)
#define R50(M) R25(M) M(25) M(26) M(27) M(28) M(29) M(30) M(31) M(32) M(33) M(34) \
               M(35) M(36) M(37) M(38) M(39) M(40) M(41) M(42) M(43) M(44) M(45) \
               M(46) M(47) M(48) M(49)

__device__ __forceinline__ float tanh_fast(float x) {
    float e = __expf(2.0f * x);                       // e^{2x}; inf/0 saturate correctly
    return 1.0f - 2.0f * __builtin_amdgcn_rcpf(e + 1.0f);
}

// coords (NB,NC,3) -> ct[(j*3+d)*NB + b]  (lane=b contiguous)
__global__ void k_transpose(const float* __restrict__ coords, float* __restrict__ ct) {
    int t = blockIdx.x * blockDim.x + threadIdx.x;
    if (t >= NBATCH * NCH * 3) return;
    int b  = t & (NBATCH - 1);
    int jd = t >> 6;
    int d  = jd % 3;
    int j  = jd / 3;
    ct[t] = coords[(b * NCH + j) * 3 + d];
}

// plain counting sort (k_mlp)
__device__ __forceinline__ void sort_k_by_type(
    const int* __restrict__ types, int n, int* tysh, int* ks, int* bins, int tid, int nthr)
{
    for (int t = tid; t < NCH; t += nthr) tysh[t] = types[t];
    __syncthreads();
    if (tid == 0) {
        for (int t = 0; t < NTYPE; ++t) bins[t] = 0;
        for (int k = 0; k < NK; ++k) { int j = (k < n) ? k : k + 1; bins[tysh[j]]++; }
        int off = 0;
        for (int t = 0; t < NTYPE; ++t) { int c = bins[t]; bins[t] = off; off += c; }
        for (int k = 0; k < NK; ++k) { int j = (k < n) ? k : k + 1; ks[bins[tysh[j]]++] = k; }
    }
    __syncthreads();
}

// padded counting sort: each 4-k chunk has ONE neighbor type; pads = -1.
// chs[chunk] = neighbor type, aux[0] = number of chunks.
__device__ __forceinline__ void sort_pad(
    const int* __restrict__ types, int n, int* tysh, int* ksp, int* chs, int* aux,
    int tid, int nthr)
{
    for (int t = tid; t < NCH; t += nthr) tysh[t] = types[t];
    __syncthreads();
    if (tid == 0) {
        int cnt[NTYPE], pos[NTYPE];
        for (int t = 0; t < NTYPE; ++t) cnt[t] = 0;
        for (int k = 0; k < NK; ++k) { int j = (k < n) ? k : k + 1; cnt[tysh[j]]++; }
        int c = 0;
        for (int t = 0; t < NTYPE; ++t) {
            pos[t] = c;
            int pc = (cnt[t] + 3) & ~3;
            for (int q = c >> 2; q < (c + pc) >> 2; ++q) chs[q] = t;
            for (int p = c + cnt[t]; p < c + pc; ++p) ksp[p] = -1;
            c += pc;
        }
        aux[0] = c >> 2;
        for (int k = 0; k < NK; ++k) { int j = (k < n) ? k : k + 1; ksp[pos[tysh[j]]++] = k; }
    }
    __syncthreads();
}

// Kernel A: unchanged round-10 structure (sorted k, wave-uniform s_load weights).
__global__ __launch_bounds__(256, 4) void k_mlp(
    const float* __restrict__ ct, const int* __restrict__ types,
    const float* __restrict__ W1, const float* __restrict__ B1,
    const float* __restrict__ W2, const float* __restrict__ B2,
    const float* __restrict__ W3, const float* __restrict__ B3,
    float* __restrict__ t1buf)
{
    __shared__ int ks[NK];
    __shared__ int tysh[NCH];
    __shared__ int bins[NTYPE];

    const int n  = blockIdx.x >> 2;
    const int qc = blockIdx.x & 3;
    const int w  = threadIdx.x >> 6;
    const int b  = threadIdx.x & 63;
    const int k0 = qc * 32 + w * 8;

    sort_k_by_type(types, n, tysh, ks, bins, threadIdx.x, 256);

    const float cx = ct[(n*3+0)*NBATCH + b];
    const float cy = ct[(n*3+1)*NBATCH + b];
    const float cz = ct[(n*3+2)*NBATCH + b];
    const int tn = __builtin_amdgcn_readfirstlane(tysh[n]);

    float t1a[12];
#define TIN(i) t1a[i] = 0.0f;
    R12(TIN)
#undef TIN

    for (int kk = 0; kk < 8; ++kk) {
        const int kidx = k0 + kk;
        if (kidx >= NK) break;
        const int sk = __builtin_amdgcn_readfirstlane(ks[kidx]);
        const int j  = (sk < n) ? sk : sk + 1;
        const int ch = __builtin_amdgcn_readfirstlane(tn * NTYPE + tysh[j]);

        const float dx = cx - ct[(j*3+0)*NBATCH + b];
        const float dy = cy - ct[(j*3+1)*NBATCH + b];
        const float dz = cz - ct[(j*3+2)*NBATCH + b];
        const float d2 = dx*dx + dy*dy + dz*dz;
        const float dd = sqrtf(d2);
        const float dinv = __builtin_amdgcn_rcpf(fmaxf(dd, 1e-12f));
        const float di2 = dinv * dinv;
        const float ax = dx * di2, ay = dy * di2, az = dz * di2;

        const float* w1r = W1 + ch * N1;
        const float* b1r = B1 + ch * N1;
        float y1[N1];
#define L1S(o) y1[o] = tanh_fast(fmaf(dinv, w1r[o], b1r[o]));
        R25(L1S)
#undef L1S

        const float* w2r = W2 + ch * (N2 * N1);
        const float* b2r = B2 + ch * N2;
        const float* w3r = W3 + ch * (N3 * N2);
        float zf[4];
        zf[0] = B3[ch*N3+0]; zf[1] = B3[ch*N3+1];
        zf[2] = B3[ch*N3+2]; zf[3] = B3[ch*N3+3];
        float r[4];
#define MLP2I(o,i) z = fmaf(w2r[(o)*N1+(i)], y1[i], z);
#define MLP2(o) { float z = b2r[o]; R25A(MLP2I,o) \
        float y2o = tanh_fast(z) + y1[(o)%N1]; \
        if ((o) < 4) r[(o)&3] = y2o; \
        zf[0] = fmaf(w3r[0*N2+(o)], y2o, zf[0]); \
        zf[1] = fmaf(w3r[1*N2+(o)], y2o, zf[1]); \
        zf[2] = fmaf(w3r[2*N2+(o)], y2o, zf[2]); \
        zf[3] = fmaf(w3r[3*N2+(o)], y2o, zf[3]); }
        R50(MLP2)
#undef MLP2
#undef MLP2I

#define O4F(f) { float o4 = tanh_fast(zf[f]) + r[f]; \
        t1a[0+(f)] = fmaf(ax, o4, t1a[0+(f)]); \
        t1a[4+(f)] = fmaf(ay, o4, t1a[4+(f)]); \
        t1a[8+(f)] = fmaf(az, o4, t1a[8+(f)]); }
        O4F(0) O4F(1) O4F(2) O4F(3)
#undef O4F
    }

    float* dst = t1buf + (n * 12) * NBATCH + b;   // [n][i][b] lane-coalesced
#define TAT(i) atomicAdd(dst + (i) * NBATCH, t1a[i]);
    R12(TAT)
#undef TAT
}

// Kernel B: block = (n, gh, kh). Uniform-channel 4-k chunks (padded sort).
// W1/B1/W2/B2 staged to LDS once per channel group (<=6x/block): P1 weight
// reads become broadcast float4 LDS loads instead of 625 s_load dwords/wave-k
// (round-10 bottleneck: scalar path saturated, occupancy+ gave no speedup).
// P2: i-chunks of 5 with w35[7][5] in SGPRs reused across a k-pair (W3 scalar
// volume /2, K$-hot since channel fixed per chunk). (512,3): VGPR cap ~84
// (P2 live ~70); LDS 62 KB caps residency at 2 blocks/CU regardless.
__global__ __launch_bounds__(512, 3) void k_res2(
    const float* __restrict__ ct, const int* __restrict__ types,
    const float* __restrict__ W1, const float* __restrict__ B1,
    const float* __restrict__ W2, const float* __restrict__ B2,
    const float* __restrict__ W3, const float* __restrict__ B3,
    const float* __restrict__ t1buf, float* __restrict__ out)
{
    __shared__ float y2t[4 * N2 * NBATCH];         // [kk][i][b] 51200 B
    __shared__ float t2s[4 * NBATCH * NAXIS];      //  4096 B
    __shared__ float w2s[N2 * W2P];                //  5600 B (rows padded to 28)
    __shared__ float w1s[N1], b1s[N1], b2s[N2];
    __shared__ int   ksp[MAXKP];
    __shared__ int   chs[MAXC4];
    __shared__ int   tysh[NCH];
    __shared__ int   aux[1];

    const int n    = blockIdx.x >> 2;
    const int gh   = (blockIdx.x >> 1) & 1;
    const int kh   = blockIdx.x & 1;
    const int w    = threadIdx.x >> 6;
    const int lane = threadIdx.x & 63;            // = b in both phases
    const int kk2  = w >> 1;                      // phase-1 k of chunk
    const int h    = w & 1;                       // phase-1 y2 half
    const int tid  = threadIdx.x;

    sort_pad(types, n, tysh, ksp, chs, aux, tid, 512);
    const int nch4 = __builtin_amdgcn_readfirstlane(aux[0]);
    const int c_lo = kh ? (nch4 >> 1) : 0;
    const int c_hi = kh ? nch4 : (nch4 >> 1);

    const int tn = __builtin_amdgcn_readfirstlane(tysh[n]);

    float t1r[12];
#define T1L(i) t1r[i] = t1buf[(n*12 + (i))*NBATCH + lane];
    R12(T1L)
#undef T1L

    const int g0 = __builtin_amdgcn_readfirstlane(w * 7);
    int gg[7];
#define GGI(gi) gg[gi] = ((g0 + (gi)) < N2) ? (g0 + (gi)) : (N2 - 1);
    R7(GGI)
#undef GGI

    float racc[7][4];
#define RIN(gi) racc[gi][0]=0.f; racc[gi][1]=0.f; racc[gi][2]=0.f; racc[gi][3]=0.f;
    R7(RIN)
#undef RIN

    float b3v[7];
    int prevty = -1;

    for (int kc = c_lo; kc < c_hi; ++kc) {
        const int tj = __builtin_amdgcn_readfirstlane(chs[kc]);
        const int ch = tn * NTYPE + tj;
        if (tj != prevty) {                        // block-uniform branch
            // stage channel weights to LDS (prev P2 done: trailing barrier)
            for (int idx = tid; idx < N2*N1; idx += 512)
                w2s[(idx / N1) * W2P + (idx % N1)] = W2[ch*(N2*N1) + idx];
            if (tid < N1) { w1s[tid] = W1[ch*N1+tid]; b1s[tid] = B1[ch*N1+tid]; }
            if (tid < N2) b2s[tid] = B2[ch*N2+tid];
#define B3L(gi) b3v[gi] = B3[ch*N3 + gh*N2 + gg[gi]];
            R7(B3L)
#undef B3L
            prevty = tj;
            __syncthreads();
        }
        const int kb = kc * 4;
        // ================= phase 1: stage y2 (+t2) for 4 k's (one channel) ========
        {
            const int sk = __builtin_amdgcn_readfirstlane(ksp[kb + kk2]);
            if (sk >= 0) {
                const int j = (sk < n) ? sk : sk + 1;
                const float dx = ct[(n*3+0)*NBATCH + lane] - ct[(j*3+0)*NBATCH + lane];
                const float dy = ct[(n*3+1)*NBATCH + lane] - ct[(j*3+1)*NBATCH + lane];
                const float dz = ct[(n*3+2)*NBATCH + lane] - ct[(j*3+2)*NBATCH + lane];
                const float d2 = dx*dx + dy*dy + dz*dz;
                const float dd = sqrtf(d2);
                const float dinv = __builtin_amdgcn_rcpf(fmaxf(dd, 1e-12f));

                if (h == 0) {
                    const float di2 = dinv * dinv;
                    const float ax = dx * di2, ay = dy * di2, az = dz * di2;
#define T2W(f) t2s[(kk2*NBATCH + lane)*NAXIS + (f)] = \
                    ax*t1r[f] + ay*t1r[4+(f)] + az*t1r[8+(f)];
                    T2W(0) T2W(1) T2W(2) T2W(3)
#undef T2W
                }

                float y1[N1];
#define L1S(o) y1[o] = tanh_fast(fmaf(dinv, w1s[o], b1s[o]));
                R25(L1S)
#undef L1S
                const int ob = h * N1;            // 0 or 25
                float* y2w = &y2t[(kk2*N2 + ob)*NBATCH + lane];
#define P1Q(oi,q) { float4 wq = *(const float4*)&w2s[(ob+(oi))*W2P + (q)*4]; \
                    z = fmaf(wq.x, y1[(q)*4+0], z); z = fmaf(wq.y, y1[(q)*4+1], z); \
                    z = fmaf(wq.z, y1[(q)*4+2], z); z = fmaf(wq.w, y1[(q)*4+3], z); }
#define P1S(oi) { float z = b2s[ob+(oi)]; \
                  P1Q(oi,0) P1Q(oi,1) P1Q(oi,2) P1Q(oi,3) P1Q(oi,4) P1Q(oi,5) \
                  z = fmaf(w2s[(ob+(oi))*W2P + 24], y1[24], z); \
                  y2w[(oi)*NBATCH] = tanh_fast(z) + y1[oi]; }
                R25(P1S)
#undef P1S
#undef P1Q
            }
        }
        __syncthreads();
        // ================= phase 2: layer 3 + contractions (channel fixed) ========
        const float* w3b = W3 + ch * (N3*N2) + (gh*N2) * N2;
        for (int kp = 0; kp < 2; ++kp) {
            const int skA = __builtin_amdgcn_readfirstlane(ksp[kb + kp*2 + 0]);
            const int skB = __builtin_amdgcn_readfirstlane(ksp[kb + kp*2 + 1]);
            if (skA < 0 && skB < 0) continue;
            const float* y2A = &y2t[((kp*2+0)*N2)*NBATCH + lane];
            const float* y2B = &y2t[((kp*2+1)*N2)*NBATCH + lane];
            float zA[7], zB[7];
#define ZIN(gi) zA[gi] = b3v[gi]; zB[gi] = b3v[gi];
            R7(ZIN)
#undef ZIN
            for (int ic = 0; ic < 10; ++ic) {
                const int io = ic * 5;
                float w35[7][5];                   // wave-uniform -> SGPRs
#define W35L(gi) w35[gi][0]=w3b[gg[gi]*N2+io+0]; w35[gi][1]=w3b[gg[gi]*N2+io+1]; \
                 w35[gi][2]=w3b[gg[gi]*N2+io+2]; w35[gi][3]=w3b[gg[gi]*N2+io+3]; \
                 w35[gi][4]=w3b[gg[gi]*N2+io+4];
                R7(W35L)
#undef W35L
                if (skA >= 0) {
                    float yv[5];
#define LDA(i) yv[i] = y2A[(io + (i))*NBATCH];
                    R5(LDA)
#undef LDA
#define FA(gi) zA[gi]=fmaf(w35[gi][0],yv[0],zA[gi]); zA[gi]=fmaf(w35[gi][1],yv[1],zA[gi]); \
               zA[gi]=fmaf(w35[gi][2],yv[2],zA[gi]); zA[gi]=fmaf(w35[gi][3],yv[3],zA[gi]); \
               zA[gi]=fmaf(w35[gi][4],yv[4],zA[gi]);
                    R7(FA)
#undef FA
                }
                if (skB >= 0) {
                    float yv[5];
#define LDB(i) yv[i] = y2B[(io + (i))*NBATCH];
                    R5(LDB)
#undef LDB
#define FB(gi) zB[gi]=fmaf(w35[gi][0],yv[0],zB[gi]); zB[gi]=fmaf(w35[gi][1],yv[1],zB[gi]); \
               zB[gi]=fmaf(w35[gi][2],yv[2],zB[gi]); zB[gi]=fmaf(w35[gi][3],yv[3],zB[gi]); \
               zB[gi]=fmaf(w35[gi][4],yv[4],zB[gi]);
                    R7(FB)
#undef FB
                }
            }
            if (skA >= 0) {
                const float4 t2v = *(const float4*)&t2s[((kp*2+0)*NBATCH + lane)*NAXIS];
#define PFA(gi) { float o3 = tanh_fast(zA[gi]) + y2A[gg[gi]*NBATCH]; \
                  racc[gi][0] = fmaf(o3, t2v.x, racc[gi][0]); \
                  racc[gi][1] = fmaf(o3, t2v.y, racc[gi][1]); \
                  racc[gi][2] = fmaf(o3, t2v.z, racc[gi][2]); \
                  racc[gi][3] = fmaf(o3, t2v.w, racc[gi][3]); }
                R7(PFA)
#undef PFA
            }
            if (skB >= 0) {
                const float4 t2v = *(const float4*)&t2s[((kp*2+1)*NBATCH + lane)*NAXIS];
#define PFB(gi) { float o3 = tanh_fast(zB[gi]) + y2B[gg[gi]*NBATCH]; \
                  racc[gi][0] = fmaf(o3, t2v.x, racc[gi][0]); \
                  racc[gi][1] = fmaf(o3, t2v.y, racc[gi][1]); \
                  racc[gi][2] = fmaf(o3, t2v.z, racc[gi][2]); \
                  racc[gi][3] = fmaf(o3, t2v.w, racc[gi][3]); }
                R7(PFB)
#undef PFB
            }
        }
        __syncthreads();
    }

#define PST(gi) if (g0 + (gi) < N2) { \
        float* dp = &out[(lane*NCH + n)*OUTPER + (gh*N2 + g0 + (gi))*NAXIS]; \
        atomicAdd(dp + 0, racc[gi][0]); \
        atomicAdd(dp + 1, racc[gi][1]); \
        atomicAdd(dp + 2, racc[gi][2]); \
        atomicAdd(dp + 3, racc[gi][3]); }
    R7(PST)
#undef PST
}

extern "C" void kernel_launch(void* const* d_in, const int* in_sizes, int n_in,
                              void* d_out, int out_size, void* d_ws, size_t ws_size,
                              hipStream_t stream) {
    const float* coords = (const float*)d_in[0];
    const int*   types  = (const int*)d_in[1];
    const float* W1 = (const float*)d_in[2];
    const float* B1 = (const float*)d_in[3];
    const float* W2 = (const float*)d_in[4];
    const float* B2 = (const float*)d_in[5];
    const float* W3 = (const float*)d_in[6];
    const float* B3 = (const float*)d_in[7];
    float* out = (float*)d_out;

    float* t1buf = (float*)d_ws;                          // 128*12*64 floats
    float* ct    = t1buf + NCH * 12 * NBATCH;             // 64*128*3 floats

    hipMemsetAsync(t1buf, 0, (size_t)NCH * 12 * NBATCH * sizeof(float), stream);
    hipMemsetAsync(out, 0, (size_t)out_size * sizeof(float), stream);

    k_transpose<<<(NBATCH*NCH*3 + 255)/256, 256, 0, stream>>>(coords, ct);
    k_mlp <<<NCH*4, 256, 0, stream>>>(ct, types, W1,B1,W2,B2,W3,B3, t1buf);
    k_res2<<<NCH*4, 512, 0, stream>>>(ct, types, W1,B1,W2,B2,W3,B3, t1buf, out);
}